// Round 1
// baseline (73.349 us; speedup 1.0000x reference)
//
#include <hip/hip_runtime.h>
#include <math.h>

#define KK 8
#define LOG2E  1.4426950408889634f
#define HL2E   0.7213475204444817f   // 0.5 * log2(e)
#define LOG2PI 1.8378770664093453f

// ---------------------------------------------------------------------------
// Kernel 1: grid = M*4 blocks x 256 threads (4 waves). Block b: m = b>>2,
// points [ (b&3)*1024, +1024 ), 4 points/thread. Small blocks + ~85 VGPR ->
// ~6 blocks/CU resident for latency hiding (R6: Occupancy 20% with big
// barrier-locked blocks).
// __builtin_amdgcn_exp2f = bare v_exp_f32 (R6: OCML exp2f expands ~2x).
// R7 change: NO memset + NO atomics. Each wave butterfly-reduces its resp
// partials and stores them to ws[(b*4+wid)*8 + k] (plain float4 stores);
// gmm_norm sums the 16 partials per (m,k). Column z-norm is scale-invariant
// so B-scaled sums are fine (R5-verified). This drops one dispatch (memset),
// the atomicAdd tail, and the final __syncthreads from the hot kernel.
// NOTE: per-point softmax MUST keep max-subtraction (R3 bug: collective exp2
// underflow zeroes responsibility mass).
// NOTE: no 2nd __launch_bounds__ arg (R4: treated as min-blocks/CU -> VGPR=64
// -> 458 MB/dispatch scratch spill).
// z layout per row: [mu(32)|logL(32)|pi(8)|resp(8)].
// ---------------------------------------------------------------------------
__global__ __launch_bounds__(256) void gmm_main(const float* __restrict__ phi,
                                                const float* __restrict__ X,
                                                float* __restrict__ z,
                                                float* __restrict__ ws) {
    __shared__ float4 sp[KK][4];   // per-component params (broadcast reads)

    const int b = blockIdx.x;
    const int m = b >> 2;
    const int sub = b & 3;
    const int t = threadIdx.x;
    const float* row = phi + m * 120;

    if (t < KK) {
        // softmax over pi_tilde (redundant across 8 lanes, cheap)
        float mx = row[0];
        #pragma unroll
        for (int j = 1; j < KK; ++j) mx = fmaxf(mx, row[j]);
        float s = 0.f;
        #pragma unroll
        for (int j = 0; j < KK; ++j) s += __expf(row[j] - mx);
        float pik = __expf(row[t] - mx) / s;
        if (sub == 0) z[m * 80 + 64 + t] = pik;          // pi columns

        const float* muk = row + 8 + t * 4;
        const float* Lv  = row + 40 + t * 10;
        // tril(D=4) order: l00,l10,l11,l20,l21,l22,l30,l31,l32,l33
        float l00 = Lv[0], l10 = Lv[1], l11 = Lv[2], l20 = Lv[3], l21 = Lv[4],
              l22 = Lv[5], l30 = Lv[6], l31 = Lv[7], l32 = Lv[8], l33 = Lv[9];
        float i0 = 1.f / l00, i1 = 1.f / l11, i2 = 1.f / l22, i3 = 1.f / l33;
        // W = inv(L), lower triangular (== forward-substitution coefficients)
        float w00 = i0;
        float w10 = -i1 * l10 * w00;
        float w11 = i1;
        float w20 = -i2 * (l20 * w00 + l21 * w10);
        float w21 = -i2 * (l21 * w11);
        float w22 = i2;
        float w30 = -i3 * (l30 * w00 + l31 * w10 + l32 * w20);
        float w31 = -i3 * (l31 * w11 + l32 * w21);
        float w32 = -i3 * (l32 * w22);
        float w33 = i3;
        float logdet = 2.f * (__logf(fmaxf(fabsf(l00), 1e-8f)) +
                              __logf(fmaxf(fabsf(l11), 1e-8f)) +
                              __logf(fmaxf(fabsf(l22), 1e-8f)) +
                              __logf(fmaxf(fabsf(l33), 1e-8f)));
        float c2 = (__logf(fmaxf(pik, 1e-8f)) -
                    0.5f * (4.f * LOG2PI + logdet)) * LOG2E;
        sp[t][0] = make_float4(muk[0], muk[1], muk[2], muk[3]);
        sp[t][1] = make_float4(w00, w10, w11, w20);
        sp[t][2] = make_float4(w21, w22, w30, w31);
        sp[t][3] = make_float4(w32, w33, c2, 0.f);
    } else if (sub == 0 && t >= 64 && t < 96) {          // mu columns
        int j = t - 64;
        z[m * 80 + j] = row[8 + j];
    } else if (sub == 0 && t >= 96 && t < 128) {         // log|L_diag| columns
        int j = t - 96, k = j >> 2, d = j & 3;
        int didx = (d == 0) ? 0 : (d == 1) ? 2 : (d == 2) ? 5 : 9;
        z[m * 80 + 32 + j] = __logf(fmaxf(fabsf(row[40 + k * 10 + didx]), 1e-6f));
    }
    __syncthreads();

    float acc[KK];
    #pragma unroll
    for (int k = 0; k < KK; ++k) acc[k] = 0.f;

    const float4* X4 = reinterpret_cast<const float4*>(X);  // 4096 rows
    float4 xv[4];
    #pragma unroll
    for (int i = 0; i < 4; ++i) xv[i] = X4[sub * 1024 + i * 256 + t];

    float lj[4][KK];
    #pragma unroll
    for (int k = 0; k < KK; ++k) {
        float4 p0 = sp[k][0], p1 = sp[k][1], p2 = sp[k][2], p3 = sp[k][3];
        // mu=p0; w00,w10,w11,w20=p1; w21,w22,w30,w31=p2; w32,w33,c2=p3
        #pragma unroll
        for (int i = 0; i < 4; ++i) {
            float d0 = xv[i].x - p0.x;
            float d1 = xv[i].y - p0.y;
            float d2 = xv[i].z - p0.z;
            float d3 = xv[i].w - p0.w;
            float a0 = d0 * p1.x;
            float a1 = fmaf(p1.y, d0, d1 * p1.z);
            float a2 = fmaf(p1.w, d0, fmaf(p2.x, d1, d2 * p2.y));
            float a3 = fmaf(p2.z, d0, fmaf(p2.w, d1, fmaf(p3.x, d2, d3 * p3.y)));
            float sq = fmaf(a0, a0, fmaf(a1, a1, fmaf(a2, a2, a3 * a3)));
            lj[i][k] = fmaf(-HL2E, sq, p3.z);             // log2-domain
        }
    }
    #pragma unroll
    for (int i = 0; i < 4; ++i) {
        float mx = lj[i][0];
        #pragma unroll
        for (int k = 1; k < KK; ++k) mx = fmaxf(mx, lj[i][k]);
        float e[KK], s = 0.f;
        #pragma unroll
        for (int k = 0; k < KK; ++k) {
            e[k] = __builtin_amdgcn_exp2f(lj[i][k] - mx); // bare v_exp_f32
            s += e[k];
        }
        float inv = __builtin_amdgcn_rcpf(s);             // s >= 1 (max term = 1)
        #pragma unroll
        for (int k = 0; k < KK; ++k) acc[k] = fmaf(e[k], inv, acc[k]);
    }

    // wave butterfly-reduce (result replicated in all 64 lanes), then lane 0
    // of each wave stores its 8 partials to ws — no barrier, no atomics.
    #pragma unroll
    for (int k = 0; k < KK; ++k) {
        float v = acc[k];
        #pragma unroll
        for (int off = 32; off; off >>= 1) v += __shfl_xor(v, off, 64);
        acc[k] = v;
    }
    if ((t & 63) == 0) {
        const int wid = t >> 6;
        float* w = ws + ((size_t)b * 4 + wid) * 8;   // = m*128 + sub*32 + wid*8
        reinterpret_cast<float4*>(w)[0] = make_float4(acc[0], acc[1], acc[2], acc[3]);
        reinterpret_cast<float4*>(w)[1] = make_float4(acc[4], acc[5], acc[6], acc[7]);
    }
}

// ---------------------------------------------------------------------------
// Kernel 2: in-place column normalization of z (M=512 rows x 80 cols), ddof=1.
// One block per column, one thread per row; element cached in a register.
// resp columns (72..79) are materialized here from the 16 per-(m,wave)
// B-scaled partials in ws — (v-mean)/std is scale-invariant.
// ---------------------------------------------------------------------------
__global__ __launch_bounds__(512) void gmm_norm(float* __restrict__ z,
                                                const float* __restrict__ ws,
                                                int M) {
    __shared__ float sw[8];
    const int col = blockIdx.x;
    const int t = threadIdx.x;

    float v;
    if (col >= 72) {                 // uniform branch (col is per-block)
        const float* w = ws + (size_t)t * 128 + (col - 72);
        float s = 0.f;
        #pragma unroll
        for (int p = 0; p < 16; ++p) s += w[p * 8];
        v = s;
    } else {
        v = z[t * 80 + col];
    }

    float r = v;
    #pragma unroll
    for (int off = 32; off; off >>= 1) r += __shfl_xor(r, off, 64);
    if ((t & 63) == 0) sw[t >> 6] = r;
    __syncthreads();
    float tot = 0.f;
    #pragma unroll
    for (int w = 0; w < 8; ++w) tot += sw[w];
    float mean = tot / (float)M;
    __syncthreads();

    float d = v - mean;
    r = d * d;
    #pragma unroll
    for (int off = 32; off; off >>= 1) r += __shfl_xor(r, off, 64);
    if ((t & 63) == 0) sw[t >> 6] = r;
    __syncthreads();
    float tot2 = 0.f;
    #pragma unroll
    for (int w = 0; w < 8; ++w) tot2 += sw[w];
    float stdv = fmaxf(sqrtf(tot2 / (float)(M - 1)), 1e-6f);

    z[t * 80 + col] = d / stdv;
}

extern "C" void kernel_launch(void* const* d_in, const int* in_sizes, int n_in,
                              void* d_out, int out_size, void* d_ws, size_t ws_size,
                              hipStream_t stream) {
    const float* phi = (const float*)d_in[0];
    const float* X   = (const float*)d_in[1];
    const int M = in_sizes[0] / 120;  // 512
    float* z  = (float*)d_out;        // z staged directly in d_out
    float* ws = (float*)d_ws;         // M*4 sub-blocks * 4 waves * 8 comps

    // No memset: every z column is written exactly once (mu/logL/pi by
    // gmm_main sub==0; resp columns materialized in gmm_norm from ws).
    gmm_main<<<M * 4, 256, 0, stream>>>(phi, X, z, ws);
    gmm_norm<<<80, 512, 0, stream>>>(z, ws, M);
}

// Round 3
// 72.006 us; speedup vs baseline: 1.0186x; 1.0186x over previous
//
#include <hip/hip_runtime.h>
#include <math.h>

#define KK 8
#define LOG2E  1.4426950408889634f
#define HL2E   0.7213475204444817f   // 0.5 * log2(e)
#define SQHL2E 0.8493217829f         // sqrt(HL2E)
#define LOG2PI 1.8378770664093453f

// ---------------------------------------------------------------------------
// R9: two-kernel structure (R7, verified) with a leaner inner loop.
// Grid = M*2 blocks x 256 threads (4 waves). Block b: m = b>>1, points
// [ (b&1)*2048, +2048 ), 8 points/thread in 2 chunks of 4.
// Param section now precomputes W' = sqrt(HL2E)*inv(L) and nv = -W'*mu, so
// per (k,point): a = W'x + nv (10 fma) and lj = c2 - sum(a^2) (4 fma with
// free neg modifiers) = 14 fma vs 19 ops before (~18% less thread VALU).
// Numerics: W'x - W'mu instead of W'(x-mu); cancellation error ~1e-3 in maha
// worst-case (tiny Cholesky pivots), threshold is 0.165 -> safe.
// R8 lesson: NO grid fusion — phase-2 reads of other blocks' z writes hit
// stale per-XCD L2 lines despite __threadfence + grid.sync (G16).
// NOTE: per-point softmax MUST keep max-subtraction (R3 bug).
// NOTE: no 2nd __launch_bounds__ arg (R4: VGPR=64 -> 458 MB scratch spill).
// z layout per row: [mu(32)|logL(32)|pi(8)|resp(8)].
// ---------------------------------------------------------------------------
__global__ __launch_bounds__(256) void gmm_main(const float* __restrict__ phi,
                                                const float* __restrict__ X,
                                                float* __restrict__ z,
                                                float* __restrict__ ws) {
    __shared__ float4 sp[KK][4];   // per-component params (broadcast reads)

    const int b = blockIdx.x;
    const int m = b >> 1;
    const int sub = b & 1;
    const int t = threadIdx.x;
    const float* row = phi + m * 120;

    if (t < KK) {
        // softmax over pi_tilde (redundant across 8 lanes, cheap)
        float mx = row[0];
        #pragma unroll
        for (int j = 1; j < KK; ++j) mx = fmaxf(mx, row[j]);
        float s = 0.f;
        #pragma unroll
        for (int j = 0; j < KK; ++j) s += __expf(row[j] - mx);
        float pik = __expf(row[t] - mx) * __builtin_amdgcn_rcpf(s);
        if (sub == 0) z[m * 80 + 64 + t] = pik;          // pi columns

        const float* muk = row + 8 + t * 4;
        const float* Lv  = row + 40 + t * 10;
        // tril(D=4) order: l00,l10,l11,l20,l21,l22,l30,l31,l32,l33
        float l00 = Lv[0], l10 = Lv[1], l11 = Lv[2], l20 = Lv[3], l21 = Lv[4],
              l22 = Lv[5], l30 = Lv[6], l31 = Lv[7], l32 = Lv[8], l33 = Lv[9];
        float i0 = __builtin_amdgcn_rcpf(l00);
        float i1 = __builtin_amdgcn_rcpf(l11);
        float i2 = __builtin_amdgcn_rcpf(l22);
        float i3 = __builtin_amdgcn_rcpf(l33);
        // W = inv(L) (forward-substitution coefficients), scaled by sqrt(HL2E)
        float w00 = i0;
        float w10 = -i1 * l10 * w00;
        float w11 = i1;
        float w20 = -i2 * (l20 * w00 + l21 * w10);
        float w21 = -i2 * (l21 * w11);
        float w22 = i2;
        float w30 = -i3 * (l30 * w00 + l31 * w10 + l32 * w20);
        float w31 = -i3 * (l31 * w11 + l32 * w21);
        float w32 = -i3 * (l32 * w22);
        float w33 = i3;
        float s00 = SQHL2E * w00, s10 = SQHL2E * w10, s11 = SQHL2E * w11,
              s20 = SQHL2E * w20, s21 = SQHL2E * w21, s22 = SQHL2E * w22,
              s30 = SQHL2E * w30, s31 = SQHL2E * w31, s32 = SQHL2E * w32,
              s33 = SQHL2E * w33;
        float m0 = muk[0], m1 = muk[1], m2 = muk[2], m3 = muk[3];
        float nv0 = -(s00 * m0);
        float nv1 = -fmaf(s10, m0, s11 * m1);
        float nv2 = -fmaf(s20, m0, fmaf(s21, m1, s22 * m2));
        float nv3 = -fmaf(s30, m0, fmaf(s31, m1, fmaf(s32, m2, s33 * m3)));
        float logdet = 2.f * (__logf(fmaxf(fabsf(l00), 1e-8f)) +
                              __logf(fmaxf(fabsf(l11), 1e-8f)) +
                              __logf(fmaxf(fabsf(l22), 1e-8f)) +
                              __logf(fmaxf(fabsf(l33), 1e-8f)));
        float c2 = (__logf(fmaxf(pik, 1e-8f)) -
                    0.5f * (4.f * LOG2PI + logdet)) * LOG2E;
        sp[t][0] = make_float4(s00, s10, s11, s20);
        sp[t][1] = make_float4(s21, s22, s30, s31);
        sp[t][2] = make_float4(s32, s33, nv0, nv1);
        sp[t][3] = make_float4(nv2, nv3, c2, 0.f);
    } else if (sub == 0 && t >= 64 && t < 96) {          // mu columns
        int j = t - 64;
        z[m * 80 + j] = row[8 + j];
    } else if (sub == 0 && t >= 96 && t < 128) {         // log|L_diag| columns
        int j = t - 96, k = j >> 2, d = j & 3;
        int didx = (d == 0) ? 0 : (d == 1) ? 2 : (d == 2) ? 5 : 9;
        z[m * 80 + 32 + j] = __logf(fmaxf(fabsf(row[40 + k * 10 + didx]), 1e-6f));
    }
    __syncthreads();

    float acc[KK];
    #pragma unroll
    for (int k = 0; k < KK; ++k) acc[k] = 0.f;

    const float4* X4 = reinterpret_cast<const float4*>(X);  // 4096 rows

    #pragma unroll
    for (int c = 0; c < 2; ++c) {
        float4 xv[4];
        #pragma unroll
        for (int i = 0; i < 4; ++i) xv[i] = X4[sub * 2048 + c * 1024 + i * 256 + t];

        float lj[4][KK];
        #pragma unroll
        for (int k = 0; k < KK; ++k) {
            float4 p0 = sp[k][0], p1 = sp[k][1], p2 = sp[k][2], p3 = sp[k][3];
            // p0=(s00,s10,s11,s20) p1=(s21,s22,s30,s31) p2=(s32,s33,nv0,nv1)
            // p3=(nv2,nv3,c2,-)
            #pragma unroll
            for (int i = 0; i < 4; ++i) {
                float x0 = xv[i].x, x1 = xv[i].y, x2 = xv[i].z, x3 = xv[i].w;
                float a0 = fmaf(p0.x, x0, p2.z);
                float a1 = fmaf(p0.y, x0, fmaf(p0.z, x1, p2.w));
                float a2 = fmaf(p0.w, x0, fmaf(p1.x, x1, fmaf(p1.y, x2, p3.x)));
                float a3 = fmaf(p1.z, x0, fmaf(p1.w, x1,
                            fmaf(p2.x, x2, fmaf(p2.y, x3, p3.y))));
                // lj = c2 - a0^2 - a1^2 - a2^2 - a3^2 (neg modifiers are free)
                lj[i][k] = fmaf(-a0, a0, fmaf(-a1, a1,
                             fmaf(-a2, a2, fmaf(-a3, a3, p3.z))));
            }
        }
        #pragma unroll
        for (int i = 0; i < 4; ++i) {
            float mx = lj[i][0];
            #pragma unroll
            for (int k = 1; k < KK; ++k) mx = fmaxf(mx, lj[i][k]);
            float e[KK], s = 0.f;
            #pragma unroll
            for (int k = 0; k < KK; ++k) {
                e[k] = __builtin_amdgcn_exp2f(lj[i][k] - mx); // bare v_exp_f32
                s += e[k];
            }
            float inv = __builtin_amdgcn_rcpf(s);         // s >= 1 (max term = 1)
            #pragma unroll
            for (int k = 0; k < KK; ++k) acc[k] = fmaf(e[k], inv, acc[k]);
        }
    }

    // wave butterfly-reduce (replicated in all lanes); lane 0 of each wave
    // stores its 8 partials to ws — no barrier, no atomics.
    #pragma unroll
    for (int k = 0; k < KK; ++k) {
        float v = acc[k];
        #pragma unroll
        for (int off = 32; off; off >>= 1) v += __shfl_xor(v, off, 64);
        acc[k] = v;
    }
    if ((t & 63) == 0) {
        const int wid = t >> 6;
        float* w = ws + ((size_t)b * 4 + wid) * 8;   // = m*64 + sub*32 + wid*8
        reinterpret_cast<float4*>(w)[0] = make_float4(acc[0], acc[1], acc[2], acc[3]);
        reinterpret_cast<float4*>(w)[1] = make_float4(acc[4], acc[5], acc[6], acc[7]);
    }
}

// ---------------------------------------------------------------------------
// Kernel 2: in-place column normalization of z (M=512 rows x 80 cols), ddof=1.
// One block per column, one thread per row; element cached in a register.
// resp columns (72..79) materialized from the 8 per-(m,sub,wave) B-scaled
// partials in ws — (v-mean)/std is scale-invariant (R5).
// ---------------------------------------------------------------------------
__global__ __launch_bounds__(512) void gmm_norm(float* __restrict__ z,
                                                const float* __restrict__ ws,
                                                int M) {
    __shared__ float sw[8];
    const int col = blockIdx.x;
    const int t = threadIdx.x;

    float v;
    if (col >= 72) {                 // uniform branch (col is per-block)
        const float* w = ws + (size_t)t * 64 + (col - 72);
        float s = 0.f;
        #pragma unroll
        for (int p = 0; p < 8; ++p) s += w[p * 8];
        v = s;
    } else {
        v = z[t * 80 + col];
    }

    float r = v;
    #pragma unroll
    for (int off = 32; off; off >>= 1) r += __shfl_xor(r, off, 64);
    if ((t & 63) == 0) sw[t >> 6] = r;
    __syncthreads();
    float tot = 0.f;
    #pragma unroll
    for (int w = 0; w < 8; ++w) tot += sw[w];
    float mean = tot / (float)M;
    __syncthreads();

    float d = v - mean;
    r = d * d;
    #pragma unroll
    for (int off = 32; off; off >>= 1) r += __shfl_xor(r, off, 64);
    if ((t & 63) == 0) sw[t >> 6] = r;
    __syncthreads();
    float tot2 = 0.f;
    #pragma unroll
    for (int w = 0; w < 8; ++w) tot2 += sw[w];
    float stdv = fmaxf(sqrtf(tot2 / (float)(M - 1)), 1e-6f);

    z[t * 80 + col] = d / stdv;
}

extern "C" void kernel_launch(void* const* d_in, const int* in_sizes, int n_in,
                              void* d_out, int out_size, void* d_ws, size_t ws_size,
                              hipStream_t stream) {
    const float* phi = (const float*)d_in[0];
    const float* X   = (const float*)d_in[1];
    const int M = in_sizes[0] / 120;  // 512
    float* z  = (float*)d_out;        // z staged directly in d_out
    float* ws = (float*)d_ws;         // M*2 sub-blocks * 4 waves * 8 comps

    gmm_main<<<M * 2, 256, 0, stream>>>(phi, X, z, ws);
    gmm_norm<<<80, 512, 0, stream>>>(z, ws, M);
}